// Round 4
// baseline (260.593 us; speedup 1.0000x reference)
//
#include <hip/hip_runtime.h>

// Head: causal MHA, B=128 T=256 C=384 H=6 d=64. Inputs fp32, output fp32.
// wtrans (W->W^T bf16, Wq pre-scaled) -> gemm_qkv (z-fused: Q,K row-major + V^T)
// -> attn (1 wave per 32 q-rows, S^T = K Q^T, O^T = V^T P^T, barrier-free).

typedef unsigned short u16;
typedef float f32x4 __attribute__((ext_vector_type(4)));
typedef short s16x8 __attribute__((ext_vector_type(8)));

static constexpr int BB = 128;
static constexpr int TT = 256;
static constexpr int CC = 384;
static constexpr int HH = 6;
static constexpr int DD = 64;
static constexpr int MM = BB * TT;  // 32768

// ws layout (u16 elements): Q [M,C] | K [M,C] | VT [B,H,D,T] | WT x3 [C,C]
static constexpr size_t QOFF  = 0;
static constexpr size_t KOFF  = (size_t)MM * CC;
static constexpr size_t VOFF  = (size_t)2 * MM * CC;
static constexpr size_t WTOFF = (size_t)3 * MM * CC;

// (1/sqrt(384)) * log2(e): folded into Wq so attn logits are already base-2
static constexpr float CSC = 0.07362242194579907f;

__device__ __forceinline__ u16 f2bf(float f) {
  unsigned u = __float_as_uint(f);
  u += 0x7fffu + ((u >> 16) & 1u);   // RTN-even
  return (u16)(u >> 16);
}

// ---------- W transpose + fp32->bf16 (Wq scaled by CSC) ----------
__global__ void wtrans(const float* __restrict__ Wq, const float* __restrict__ Wk,
                       const float* __restrict__ Wv, u16* __restrict__ ws) {
  const float* W = (blockIdx.y == 0) ? Wq : (blockIdx.y == 1) ? Wk : Wv;
  const float sc = (blockIdx.y == 0) ? CSC : 1.0f;
  u16* WT = ws + WTOFF + (size_t)blockIdx.y * CC * CC;
  int i = blockIdx.x * 256 + threadIdx.x;
  int k = i / CC, n = i % CC;
  WT[(size_t)n * CC + k] = f2bf(W[i] * sc);
}

// ---------- z-fused QKV projection ----------
// Block: 128m x 128n, 512 thr = 8 waves of 32m x 64n; A staged once, B frags from L2.
__global__ __launch_bounds__(512) void gemm_qkv(const float* __restrict__ X,
                                                u16* __restrict__ ws) {
  __shared__ u16 As[128][72];

  const int tid = threadIdx.x;
  const int lane = tid & 63;
  const int w = tid >> 6;
  const int quad = lane >> 4;
  const int col = lane & 15;
  const int m0 = blockIdx.x * 128;
  const int n0 = blockIdx.y * 128;
  const int wm = (w & 3) * 32;
  const int wn = (w >> 2) * 64;

  f32x4 acc[3][2][4] = {};

  for (int kt = 0; kt < 6; ++kt) {
    if (kt) __syncthreads();
#pragma unroll
    for (int i = 0; i < 2; ++i) {
      int c = i * 512 + tid;
      int row = c >> 3, c8 = (c & 7) * 8;
      f32x4 a0 = *(const f32x4*)(X + (size_t)(m0 + row) * CC + kt * 64 + c8);
      f32x4 a1 = *(const f32x4*)(X + (size_t)(m0 + row) * CC + kt * 64 + c8 + 4);
      s16x8 ab;
#pragma unroll
      for (int j = 0; j < 4; ++j) { ab[j] = (short)f2bf(a0[j]); ab[4 + j] = (short)f2bf(a1[j]); }
      *(s16x8*)(&As[row][c8]) = ab;
    }
    __syncthreads();

    s16x8 af[2][2];
#pragma unroll
    for (int mt = 0; mt < 2; ++mt)
#pragma unroll
      for (int ks = 0; ks < 2; ++ks)
        af[mt][ks] = *(const s16x8*)(&As[wm + mt * 16 + col][ks * 32 + quad * 8]);

#pragma unroll
    for (int z = 0; z < 3; ++z) {
      const u16* WT = ws + WTOFF + (size_t)z * CC * CC;
      s16x8 bf[4][2];
#pragma unroll
      for (int nt = 0; nt < 4; ++nt)
#pragma unroll
        for (int ks = 0; ks < 2; ++ks)
          bf[nt][ks] = *(const s16x8*)(WT + (size_t)(n0 + wn + nt * 16 + col) * CC +
                                       kt * 64 + ks * 32 + quad * 8);
#pragma unroll
      for (int ks = 0; ks < 2; ++ks)
#pragma unroll
        for (int mt = 0; mt < 2; ++mt)
#pragma unroll
          for (int nt = 0; nt < 4; ++nt)
            acc[z][mt][nt] = __builtin_amdgcn_mfma_f32_16x16x32_bf16(
                af[mt][ks], bf[nt][ks], acc[z][mt][nt], 0, 0, 0);
    }
  }

  // epilogues: z=0,1 -> Q,K row-major; z=2 -> V^T [b][h][d][t] (8B packed over tokens)
#pragma unroll
  for (int z = 0; z < 2; ++z) {
    u16* Y = ws + (size_t)z * MM * CC;
#pragma unroll
    for (int mt = 0; mt < 2; ++mt)
#pragma unroll
      for (int nt = 0; nt < 4; ++nt) {
        int mg = m0 + wm + mt * 16 + quad * 4;
        int ng = n0 + wn + nt * 16 + col;
#pragma unroll
        for (int r = 0; r < 4; ++r)
          Y[(size_t)(mg + r) * CC + ng] = f2bf(acc[z][mt][nt][r]);
      }
  }
#pragma unroll
  for (int mt = 0; mt < 2; ++mt)
#pragma unroll
    for (int nt = 0; nt < 4; ++nt) {
      int tok = m0 + wm + mt * 16 + quad * 4;
      int bb = tok >> 8, t = tok & 255;
      int ng = n0 + wn + nt * 16 + col;
      int hh = ng >> 6, d = ng & 63;
      uint2 pk;
      pk.x = (unsigned)f2bf(acc[2][mt][nt][0]) | ((unsigned)f2bf(acc[2][mt][nt][1]) << 16);
      pk.y = (unsigned)f2bf(acc[2][mt][nt][2]) | ((unsigned)f2bf(acc[2][mt][nt][3]) << 16);
      *(uint2*)(ws + VOFF + (((size_t)(bb * HH + hh) * DD + d) * TT + t)) = pk;
    }
}

// ---------- Flash attention: 128-thr block = 2 indep waves, each 32 q-rows ----------
// qt = 3 - bx/768 (heavy first; 768%8==0 -> uniform qt per XCD, same-bh same-XCD).
__global__ __launch_bounds__(128) void attn(const u16* __restrict__ ws,
                                            float* __restrict__ out) {
  const int bx = blockIdx.x;
  const int qt = 3 - (bx / 768);
  const int bh = bx % 768;
  const int b = bh / HH;
  const int h = bh % HH;

  __shared__ u16 Ps[2][16][72];   // per-wave P^T round-trip: [q][key]

  const int tid = threadIdx.x;
  const int lane = tid & 63;
  const int w = tid >> 6;
  const int quad = lane >> 4;
  const int col = lane & 15;
  const int q0 = qt * 64 + w * 32;   // this wave's 32 q-rows

  const u16* Qg = ws + QOFF;
  const u16* Kg = ws + KOFF;
  const u16* VTg = ws + VOFF;

  // Q B-frags hoisted (pre-scaled by CSC): [n=q=col][k=d]
  s16x8 qf[2][2];
#pragma unroll
  for (int mt = 0; mt < 2; ++mt)
#pragma unroll
    for (int ks = 0; ks < 2; ++ks)
      qf[mt][ks] = *(const s16x8*)(Qg + (size_t)(b * TT + q0 + mt * 16 + col) * CC +
                                   h * DD + ks * 32 + quad * 8);

  f32x4 o[2][4] = {};          // O^T acc: [mt(q16)][dt(d16)]
  float mst[2] = {-1.0e30f, -1.0e30f}, lst[2] = {0.0f, 0.0f};

  for (int kt = 0; kt <= qt; ++kt) {
    // K A-frags: [key = nt*16+col][d]; V^T A-frags: [d = dt*16+col][key]
    s16x8 kf[4][2], vf[4][2];
#pragma unroll
    for (int nt = 0; nt < 4; ++nt)
#pragma unroll
      for (int ks = 0; ks < 2; ++ks) {
        kf[nt][ks] = *(const s16x8*)(Kg + (size_t)(b * TT + kt * 64 + nt * 16 + col) * CC +
                                     h * DD + ks * 32 + quad * 8);
        vf[nt][ks] = *(const s16x8*)(VTg + ((size_t)(bh * DD + nt * 16 + col) * TT +
                                     kt * 64 + ks * 32 + quad * 8));
      }

#pragma unroll
    for (int mt = 0; mt < 2; ++mt) {
      // S^T tiles: row = key = nt*16+quad*4+r, col = q
      f32x4 s[4] = {};
#pragma unroll
      for (int ks = 0; ks < 2; ++ks)
#pragma unroll
        for (int nt = 0; nt < 4; ++nt)
          s[nt] = __builtin_amdgcn_mfma_f32_16x16x32_bf16(kf[nt][ks], qf[mt][ks],
                                                          s[nt], 0, 0, 0);

      // causal mask (diagonal kt only) + per-lane max over this lane's 16 keys
      float rmax = -1.0e30f;
#pragma unroll
      for (int nt = 0; nt < 4; ++nt)
#pragma unroll
        for (int r = 0; r < 4; ++r) {
          float t = s[nt][r];
          if (kt == qt && (nt * 16 + quad * 4 + r) > (q0 - qt * 64 + mt * 16 + col)) t = -1.0e30f;
          s[nt][r] = t;
          rmax = fmaxf(rmax, t);
        }
      rmax = fmaxf(rmax, __shfl_xor(rmax, 16));
      rmax = fmaxf(rmax, __shfl_xor(rmax, 32));

      float mn = fmaxf(mst[mt], rmax);
      float alpha = exp2f(mst[mt] - mn);
      mst[mt] = mn;

      float lsum = 0.0f;
      unsigned pk[4][2];
#pragma unroll
      for (int nt = 0; nt < 4; ++nt) {
        float p0 = exp2f(s[nt][0] - mn), p1 = exp2f(s[nt][1] - mn);
        float p2 = exp2f(s[nt][2] - mn), p3 = exp2f(s[nt][3] - mn);
        lsum += (p0 + p1) + (p2 + p3);
        pk[nt][0] = (unsigned)f2bf(p0) | ((unsigned)f2bf(p1) << 16);
        pk[nt][1] = (unsigned)f2bf(p2) | ((unsigned)f2bf(p3) << 16);
      }
      lst[mt] = lst[mt] * alpha + lsum;

#pragma unroll
      for (int dt = 0; dt < 4; ++dt)
#pragma unroll
        for (int r = 0; r < 4; ++r) o[dt == 0 ? mt : mt][dt][r] *= alpha;  // o[mt][dt]

      // P^T -> LDS [q][key]: 4 consecutive keys per lane -> b64 writes
      asm volatile("s_waitcnt lgkmcnt(0)" ::: "memory");  // WAR vs prev reads
#pragma unroll
      for (int nt = 0; nt < 4; ++nt)
        *(uint2*)(&Ps[w][col][nt * 16 + quad * 4]) = make_uint2(pk[nt][0], pk[nt][1]);
      asm volatile("s_waitcnt lgkmcnt(0)" ::: "memory");  // own-wave visibility

      s16x8 pf[2];
#pragma unroll
      for (int ks = 0; ks < 2; ++ks)
        pf[ks] = *(const s16x8*)(&Ps[w][col][ks * 32 + quad * 8]);

#pragma unroll
      for (int ks = 0; ks < 2; ++ks)
#pragma unroll
        for (int dt = 0; dt < 4; ++dt)
          o[mt][dt] = __builtin_amdgcn_mfma_f32_16x16x32_bf16(vf[dt][ks], pf[ks],
                                                              o[mt][dt], 0, 0, 0);
    }
  }

  // epilogue: O^T row = d = dt*16+quad*4+r, col = q -> out[b,q,h*64+d]
#pragma unroll
  for (int mt = 0; mt < 2; ++mt) {
    float l = lst[mt];
    l += __shfl_xor(l, 16);
    l += __shfl_xor(l, 32);
    float inv = 1.0f / l;
    int q = q0 + mt * 16 + col;
#pragma unroll
    for (int dt = 0; dt < 4; ++dt) {
      f32x4 res;
#pragma unroll
      for (int r = 0; r < 4; ++r) res[r] = o[mt][dt][r] * inv;
      *(f32x4*)(out + (size_t)(b * TT + q) * CC + h * DD + dt * 16 + quad * 4) = res;
    }
  }
}

extern "C" void kernel_launch(void* const* d_in, const int* in_sizes, int n_in,
                              void* d_out, int out_size, void* d_ws, size_t ws_size,
                              hipStream_t stream) {
  const float* x  = (const float*)d_in[0];
  const float* wq = (const float*)d_in[1];
  const float* wk = (const float*)d_in[2];
  const float* wv = (const float*)d_in[3];
  u16* ws  = (u16*)d_ws;
  float* out = (float*)d_out;

  wtrans<<<dim3(CC * CC / 256, 3), 256, 0, stream>>>(wq, wk, wv, ws);
  gemm_qkv<<<dim3(MM / 128, CC / 128), 512, 0, stream>>>(x, ws);
  attn<<<dim3(BB * HH * 4), 128, 0, stream>>>(ws, out);
}

// Round 5
// 183.959 us; speedup vs baseline: 1.4166x; 1.4166x over previous
//
#include <hip/hip_runtime.h>

// Head: causal MHA, B=128 T=256 C=384 H=6 d=64. Inputs fp32, output fp32.
// xconv (X->bf16) + wtrans (W->W^T bf16, Wq pre-scaled)
// -> gemm_qkv (single GEMM over N'=1152, LDS-staged both operands; V-part -> V^T)
// -> attn (2-wave blocks, 32 q-rows/wave, S^T = K Q^T, O^T = V^T P^T, barrier-free).

typedef unsigned short u16;
typedef float f32x4 __attribute__((ext_vector_type(4)));
typedef short s16x8 __attribute__((ext_vector_type(8)));

static constexpr int BB = 128;
static constexpr int TT = 256;
static constexpr int CC = 384;
static constexpr int HH = 6;
static constexpr int DD = 64;
static constexpr int MM = BB * TT;  // 32768

// ws layout (u16 elements): Q [M,C] | K [M,C] | VT [B,H,D,T] | WT3 [1152,384] | Xbf [M,C]
static constexpr size_t QOFF  = 0;
static constexpr size_t KOFF  = (size_t)MM * CC;
static constexpr size_t VOFF  = (size_t)2 * MM * CC;
static constexpr size_t WTOFF = (size_t)3 * MM * CC;
static constexpr size_t XOFF  = WTOFF + (size_t)3 * CC * CC;

// (1/sqrt(384)) * log2(e): folded into Wq so attn logits are already base-2
static constexpr float CSC = 0.07362242194579907f;

__device__ __forceinline__ u16 f2bf(float f) {
  unsigned u = __float_as_uint(f);
  u += 0x7fffu + ((u >> 16) & 1u);   // RTN-even
  return (u16)(u >> 16);
}

// ---------- X fp32 -> bf16 (coalesced, 8 elems/thread) ----------
__global__ void xconv(const float* __restrict__ X, u16* __restrict__ ws) {
  size_t i = (size_t)(blockIdx.x * 256 + threadIdx.x) * 8;
  f32x4 a0 = *(const f32x4*)(X + i);
  f32x4 a1 = *(const f32x4*)(X + i + 4);
  s16x8 ab;
#pragma unroll
  for (int j = 0; j < 4; ++j) { ab[j] = (short)f2bf(a0[j]); ab[4 + j] = (short)f2bf(a1[j]); }
  *(s16x8*)(ws + XOFF + i) = ab;
}

// ---------- W transpose + fp32->bf16 (Wq scaled by CSC) ----------
__global__ void wtrans(const float* __restrict__ Wq, const float* __restrict__ Wk,
                       const float* __restrict__ Wv, u16* __restrict__ ws) {
  const float* W = (blockIdx.y == 0) ? Wq : (blockIdx.y == 1) ? Wk : Wv;
  const float sc = (blockIdx.y == 0) ? CSC : 1.0f;
  u16* WT = ws + WTOFF + (size_t)blockIdx.y * CC * CC;
  int i = blockIdx.x * 256 + threadIdx.x;
  int k = i / CC, n = i % CC;
  WT[(size_t)n * CC + k] = f2bf(W[i] * sc);
}

// ---------- QKV projection as one GEMM: [M,384] @ WT3^T -> N'=1152 ----------
// Grid (m=256, n'=9) m-major: the 9 n-blocks of one m-slab land on one XCD (256%8==0)
// -> Xbf slab re-reads are L2 hits. 128x128 tile, BK=64, 4 waves of 64x64.
__global__ __launch_bounds__(256) void gemm_qkv(u16* __restrict__ ws) {
  const u16* Xbf = ws + XOFF;
  const u16* WT3 = ws + WTOFF;

  __shared__ u16 As[128][72];  // +8 pad: 2-way bank alias only (free)
  __shared__ u16 Bs[128][72];

  const int tid = threadIdx.x;
  const int lane = tid & 63;
  const int w = tid >> 6;
  const int quad = lane >> 4;
  const int col = lane & 15;
  const int m0 = blockIdx.x * 128;
  const int n0 = blockIdx.y * 128;      // n' in [0,1152)
  const int z = blockIdx.y / 3;         // 0:Q 1:K 2:V
  const int wm = (w >> 1) * 64;
  const int wn = (w & 1) * 64;

  f32x4 acc[4][4] = {};

  for (int kt = 0; kt < 6; ++kt) {
    if (kt) __syncthreads();
#pragma unroll
    for (int i = 0; i < 4; ++i) {
      int c = i * 256 + tid;
      int row = c >> 3, c8 = (c & 7) * 8;
      *(uint4*)(&As[row][c8]) =
          *(const uint4*)(Xbf + (size_t)(m0 + row) * CC + kt * 64 + c8);
      *(uint4*)(&Bs[row][c8]) =
          *(const uint4*)(WT3 + (size_t)(n0 + row) * CC + kt * 64 + c8);
    }
    __syncthreads();

    s16x8 af[4][2], bf[4][2];
#pragma unroll
    for (int mt = 0; mt < 4; ++mt)
#pragma unroll
      for (int ks = 0; ks < 2; ++ks)
        af[mt][ks] = *(const s16x8*)(&As[wm + mt * 16 + col][ks * 32 + quad * 8]);
#pragma unroll
    for (int nt = 0; nt < 4; ++nt)
#pragma unroll
      for (int ks = 0; ks < 2; ++ks)
        bf[nt][ks] = *(const s16x8*)(&Bs[wn + nt * 16 + col][ks * 32 + quad * 8]);

#pragma unroll
    for (int ks = 0; ks < 2; ++ks)
#pragma unroll
      for (int mt = 0; mt < 4; ++mt)
#pragma unroll
        for (int nt = 0; nt < 4; ++nt)
          acc[mt][nt] = __builtin_amdgcn_mfma_f32_16x16x32_bf16(
              af[mt][ks], bf[nt][ks], acc[mt][nt], 0, 0, 0);
  }

  if (z == 2) {
    // V^T epilogue: [b][h][d][t]; C/D rows are tokens (quad*4+r consecutive) -> 8B packed
#pragma unroll
    for (int mt = 0; mt < 4; ++mt)
#pragma unroll
      for (int nt = 0; nt < 4; ++nt) {
        int tok = m0 + wm + mt * 16 + quad * 4;
        int bb = tok >> 8, t = tok & 255;
        int ng = (n0 - 2 * CC) + wn + nt * 16 + col;   // within-z column
        int hh = ng >> 6, d = ng & 63;
        uint2 pk;
        pk.x = (unsigned)f2bf(acc[mt][nt][0]) | ((unsigned)f2bf(acc[mt][nt][1]) << 16);
        pk.y = (unsigned)f2bf(acc[mt][nt][2]) | ((unsigned)f2bf(acc[mt][nt][3]) << 16);
        *(uint2*)(ws + VOFF + (((size_t)(bb * HH + hh) * DD + d) * TT + t)) = pk;
      }
  } else {
    u16* Y = ws + (size_t)z * MM * CC;
    const int nz = n0 - z * CC;
#pragma unroll
    for (int mt = 0; mt < 4; ++mt)
#pragma unroll
      for (int nt = 0; nt < 4; ++nt) {
        int mg = m0 + wm + mt * 16 + quad * 4;
        int ng = nz + wn + nt * 16 + col;
#pragma unroll
        for (int r = 0; r < 4; ++r)
          Y[(size_t)(mg + r) * CC + ng] = f2bf(acc[mt][nt][r]);
      }
  }
}

// ---------- Flash attention: 128-thr block = 2 indep waves, each 32 q-rows ----------
// qt = 3 - bx/768 (heavy first; 768%8==0 -> uniform qt per XCD, same-bh same-XCD).
__global__ __launch_bounds__(128) void attn(const u16* __restrict__ ws,
                                            float* __restrict__ out) {
  const int bx = blockIdx.x;
  const int qt = 3 - (bx / 768);
  const int bh = bx % 768;
  const int b = bh / HH;
  const int h = bh % HH;

  __shared__ u16 Ps[2][16][72];   // per-wave P^T round-trip: [q][key]

  const int tid = threadIdx.x;
  const int lane = tid & 63;
  const int w = tid >> 6;
  const int quad = lane >> 4;
  const int col = lane & 15;
  const int q0 = qt * 64 + w * 32;   // this wave's 32 q-rows

  const u16* Qg = ws + QOFF;
  const u16* Kg = ws + KOFF;
  const u16* VTg = ws + VOFF;

  // Q B-frags hoisted (pre-scaled by CSC): [n=q=col][k=d]
  s16x8 qf[2][2];
#pragma unroll
  for (int mt = 0; mt < 2; ++mt)
#pragma unroll
    for (int ks = 0; ks < 2; ++ks)
      qf[mt][ks] = *(const s16x8*)(Qg + (size_t)(b * TT + q0 + mt * 16 + col) * CC +
                                   h * DD + ks * 32 + quad * 8);

  f32x4 o[2][4] = {};          // O^T acc: [mt(q16)][dt(d16)]
  float mst[2] = {-1.0e30f, -1.0e30f}, lst[2] = {0.0f, 0.0f};

  for (int kt = 0; kt <= qt; ++kt) {
    // K A-frags: [key = nt*16+col][d]; V^T A-frags: [d = nt*16+col][key]
    s16x8 kf[4][2], vf[4][2];
#pragma unroll
    for (int nt = 0; nt < 4; ++nt)
#pragma unroll
      for (int ks = 0; ks < 2; ++ks) {
        kf[nt][ks] = *(const s16x8*)(Kg + (size_t)(b * TT + kt * 64 + nt * 16 + col) * CC +
                                     h * DD + ks * 32 + quad * 8);
        vf[nt][ks] = *(const s16x8*)(VTg + ((size_t)(bh * DD + nt * 16 + col) * TT +
                                     kt * 64 + ks * 32 + quad * 8));
      }

#pragma unroll
    for (int mt = 0; mt < 2; ++mt) {
      // S^T tiles: row = key = nt*16+quad*4+r, col = q
      f32x4 s[4] = {};
#pragma unroll
      for (int ks = 0; ks < 2; ++ks)
#pragma unroll
        for (int nt = 0; nt < 4; ++nt)
          s[nt] = __builtin_amdgcn_mfma_f32_16x16x32_bf16(kf[nt][ks], qf[mt][ks],
                                                          s[nt], 0, 0, 0);

      // causal mask (diagonal kt only) + per-lane max over this lane's 16 keys
      float rmax = -1.0e30f;
#pragma unroll
      for (int nt = 0; nt < 4; ++nt)
#pragma unroll
        for (int r = 0; r < 4; ++r) {
          float t = s[nt][r];
          if (kt == qt && (nt * 16 + quad * 4 + r) > (w * 32 + mt * 16 + col)) t = -1.0e30f;
          s[nt][r] = t;
          rmax = fmaxf(rmax, t);
        }
      rmax = fmaxf(rmax, __shfl_xor(rmax, 16));
      rmax = fmaxf(rmax, __shfl_xor(rmax, 32));

      float mn = fmaxf(mst[mt], rmax);
      float alpha = exp2f(mst[mt] - mn);
      mst[mt] = mn;

      float lsum = 0.0f;
      unsigned pk[4][2];
#pragma unroll
      for (int nt = 0; nt < 4; ++nt) {
        float p0 = exp2f(s[nt][0] - mn), p1 = exp2f(s[nt][1] - mn);
        float p2 = exp2f(s[nt][2] - mn), p3 = exp2f(s[nt][3] - mn);
        lsum += (p0 + p1) + (p2 + p3);
        pk[nt][0] = (unsigned)f2bf(p0) | ((unsigned)f2bf(p1) << 16);
        pk[nt][1] = (unsigned)f2bf(p2) | ((unsigned)f2bf(p3) << 16);
      }
      lst[mt] = lst[mt] * alpha + lsum;

#pragma unroll
      for (int dt = 0; dt < 4; ++dt)
#pragma unroll
        for (int r = 0; r < 4; ++r) o[mt][dt][r] *= alpha;

      // P^T -> LDS [q][key]: 4 consecutive keys per lane -> b64 writes
      asm volatile("s_waitcnt lgkmcnt(0)" ::: "memory");  // WAR vs prev reads
#pragma unroll
      for (int nt = 0; nt < 4; ++nt)
        *(uint2*)(&Ps[w][col][nt * 16 + quad * 4]) = make_uint2(pk[nt][0], pk[nt][1]);
      asm volatile("s_waitcnt lgkmcnt(0)" ::: "memory");  // own-wave visibility

      s16x8 pf[2];
#pragma unroll
      for (int ks = 0; ks < 2; ++ks)
        pf[ks] = *(const s16x8*)(&Ps[w][col][ks * 32 + quad * 8]);

#pragma unroll
      for (int ks = 0; ks < 2; ++ks)
#pragma unroll
        for (int dt = 0; dt < 4; ++dt)
          o[mt][dt] = __builtin_amdgcn_mfma_f32_16x16x32_bf16(vf[dt][ks], pf[ks],
                                                              o[mt][dt], 0, 0, 0);
    }
  }

  // epilogue: O^T row = d = dt*16+quad*4+r, col = q -> out[b,q,h*64+d]
#pragma unroll
  for (int mt = 0; mt < 2; ++mt) {
    float l = lst[mt];
    l += __shfl_xor(l, 16);
    l += __shfl_xor(l, 32);
    float inv = 1.0f / l;
    int q = q0 + mt * 16 + col;
#pragma unroll
    for (int dt = 0; dt < 4; ++dt) {
      f32x4 res;
#pragma unroll
      for (int r = 0; r < 4; ++r) res[r] = o[mt][dt][r] * inv;
      *(f32x4*)(out + (size_t)(b * TT + q) * CC + h * DD + dt * 16 + quad * 4) = res;
    }
  }
}

extern "C" void kernel_launch(void* const* d_in, const int* in_sizes, int n_in,
                              void* d_out, int out_size, void* d_ws, size_t ws_size,
                              hipStream_t stream) {
  const float* x  = (const float*)d_in[0];
  const float* wq = (const float*)d_in[1];
  const float* wk = (const float*)d_in[2];
  const float* wv = (const float*)d_in[3];
  u16* ws  = (u16*)d_ws;
  float* out = (float*)d_out;

  xconv<<<dim3(MM * CC / (256 * 8)), 256, 0, stream>>>(x, ws);
  wtrans<<<dim3(CC * CC / 256, 3), 256, 0, stream>>>(wq, wk, wv, ws);
  gemm_qkv<<<dim3(MM / 128, 9), 256, 0, stream>>>(ws);
  attn<<<dim3(BB * HH * 4), 128, 0, stream>>>(ws, out);
}

// Round 6
// 180.313 us; speedup vs baseline: 1.4452x; 1.0202x over previous
//
#include <hip/hip_runtime.h>

// Head: causal MHA, B=128 T=256 C=384 H=6 d=64. Inputs fp32, output fp32.
// prep (X->bf16 + W->W^T bf16, Wq pre-scaled)
// -> gemm_qkv (one GEMM over N'=1152; global_load_lds(16B) + XOR-swizzled LDS; V->V^T)
// -> attn (2-wave blocks, 32 q-rows/wave, S^T = K Q^T, O^T = V^T P^T, barrier-free).

typedef unsigned short u16;
typedef float f32x4 __attribute__((ext_vector_type(4)));
typedef short s16x8 __attribute__((ext_vector_type(8)));

static constexpr int BB = 128;
static constexpr int TT = 256;
static constexpr int CC = 384;
static constexpr int HH = 6;
static constexpr int DD = 64;
static constexpr int MM = BB * TT;  // 32768

// ws layout (u16 elements): Q [M,C] | K [M,C] | VT [B,H,D,T] | WT3 [1152,384] | Xbf [M,C]
static constexpr size_t QOFF  = 0;
static constexpr size_t KOFF  = (size_t)MM * CC;
static constexpr size_t VOFF  = (size_t)2 * MM * CC;
static constexpr size_t WTOFF = (size_t)3 * MM * CC;
static constexpr size_t XOFF  = WTOFF + (size_t)3 * CC * CC;

// (1/sqrt(384)) * log2(e): folded into Wq so attn logits are already base-2
static constexpr float CSC = 0.07362242194579907f;

__device__ __forceinline__ u16 f2bf(float f) {
  unsigned u = __float_as_uint(f);
  u += 0x7fffu + ((u >> 16) & 1u);   // RTN-even
  return (u16)(u >> 16);
}

// async global->LDS, 16 B/lane; LDS dest = wave-uniform base + lane*16 (m104)
__device__ __forceinline__ void g2l16(const u16* g, u16* l) {
  __builtin_amdgcn_global_load_lds(
      (const __attribute__((address_space(1))) u16*)g,
      (__attribute__((address_space(3))) u16*)l, 16, 0, 0);
}

// ---------- prep: X fp32->bf16 (blocks 0..6143) + W^T (blocks 6144..7871) ----------
__global__ void prep(const float* __restrict__ X, const float* __restrict__ Wq,
                     const float* __restrict__ Wk, const float* __restrict__ Wv,
                     u16* __restrict__ ws) {
  int bx = blockIdx.x;
  if (bx < 6144) {
    size_t i = (size_t)(bx * 256 + threadIdx.x) * 8;
    f32x4 a0 = *(const f32x4*)(X + i);
    f32x4 a1 = *(const f32x4*)(X + i + 4);
    s16x8 ab;
#pragma unroll
    for (int j = 0; j < 4; ++j) { ab[j] = (short)f2bf(a0[j]); ab[4 + j] = (short)f2bf(a1[j]); }
    *(s16x8*)(ws + XOFF + i) = ab;
  } else {
    int j = bx - 6144;
    int z = j / 576;
    const float* W = (z == 0) ? Wq : (z == 1) ? Wk : Wv;
    const float sc = (z == 0) ? CSC : 1.0f;
    u16* WT = ws + WTOFF + (size_t)z * CC * CC;
    int i = (j % 576) * 256 + threadIdx.x;
    int k = i / CC, n = i % CC;
    WT[(size_t)n * CC + k] = f2bf(W[i] * sc);
  }
}

// ---------- QKV projection as one GEMM: [M,384] @ WT3^T -> N'=1152 ----------
// Grid (m=256, n'=9) m-major: 9 n-blocks of one m-slab share an XCD (ids differ by 256).
// 128x128 tile, BK=64, 4 waves of 64x64. Tiles unpadded [128][64], XOR-swizzled:
// global block gb of row r stored at block gb^(r&7) -> staging stays contiguous for
// global_load_lds, fragment reads are 2-way bank aliased (free).
__global__ __launch_bounds__(256) void gemm_qkv(u16* __restrict__ ws) {
  const u16* Xbf = ws + XOFF;
  const u16* WT3 = ws + WTOFF;

  __shared__ u16 As[128][64];
  __shared__ u16 Bs[128][64];

  const int tid = threadIdx.x;
  const int lane = tid & 63;
  const int w = tid >> 6;
  const int quad = lane >> 4;
  const int col = lane & 15;
  const int m0 = blockIdx.x * 128;
  const int n0 = blockIdx.y * 128;      // n' in [0,1152)
  const int z = blockIdx.y / 3;         // 0:Q 1:K 2:V
  const int wm = (w >> 1) * 64;
  const int wn = (w & 1) * 64;

  const int rl = lane >> 3;             // row within 8-row chunk
  const int gb = (lane & 7) ^ rl;       // swizzled global block for this lane

  f32x4 acc[4][4] = {};

  for (int kt = 0; kt < 6; ++kt) {
    if (kt) __syncthreads();            // WAR: all waves done reading prev tile
#pragma unroll
    for (int i = 0; i < 4; ++i) {
      int r0 = (w * 4 + i) * 8;         // wave-uniform chunk base (8 rows)
      g2l16(Xbf + (size_t)(m0 + r0 + rl) * CC + kt * 64 + gb * 8, &As[r0][0]);
      g2l16(WT3 + (size_t)(n0 + r0 + rl) * CC + kt * 64 + gb * 8, &Bs[r0][0]);
    }
    __syncthreads();                    // drains vmcnt(0) then barrier (RAW)

    s16x8 af[4][2], bf[4][2];
#pragma unroll
    for (int mt = 0; mt < 4; ++mt)
#pragma unroll
      for (int ks = 0; ks < 2; ++ks)
        af[mt][ks] = *(const s16x8*)(&As[wm + mt * 16 + col]
                                        [(((ks * 4 + quad) ^ (col & 7)) * 8)]);
#pragma unroll
    for (int nt = 0; nt < 4; ++nt)
#pragma unroll
      for (int ks = 0; ks < 2; ++ks)
        bf[nt][ks] = *(const s16x8*)(&Bs[wn + nt * 16 + col]
                                        [(((ks * 4 + quad) ^ (col & 7)) * 8)]);

#pragma unroll
    for (int ks = 0; ks < 2; ++ks)
#pragma unroll
      for (int mt = 0; mt < 4; ++mt)
#pragma unroll
        for (int nt = 0; nt < 4; ++nt)
          acc[mt][nt] = __builtin_amdgcn_mfma_f32_16x16x32_bf16(
              af[mt][ks], bf[nt][ks], acc[mt][nt], 0, 0, 0);
  }

  if (z == 2) {
    // V^T epilogue: [b][h][d][t]; C/D rows are tokens (quad*4+r consecutive) -> 8B packed
#pragma unroll
    for (int mt = 0; mt < 4; ++mt)
#pragma unroll
      for (int nt = 0; nt < 4; ++nt) {
        int tok = m0 + wm + mt * 16 + quad * 4;
        int bb = tok >> 8, t = tok & 255;
        int ng = (n0 - 2 * CC) + wn + nt * 16 + col;   // within-z column
        int hh = ng >> 6, d = ng & 63;
        uint2 pk;
        pk.x = (unsigned)f2bf(acc[mt][nt][0]) | ((unsigned)f2bf(acc[mt][nt][1]) << 16);
        pk.y = (unsigned)f2bf(acc[mt][nt][2]) | ((unsigned)f2bf(acc[mt][nt][3]) << 16);
        *(uint2*)(ws + VOFF + (((size_t)(bb * HH + hh) * DD + d) * TT + t)) = pk;
      }
  } else {
    u16* Y = ws + (size_t)z * MM * CC;
    const int nz = n0 - z * CC;
#pragma unroll
    for (int mt = 0; mt < 4; ++mt)
#pragma unroll
      for (int nt = 0; nt < 4; ++nt) {
        int mg = m0 + wm + mt * 16 + quad * 4;
        int ng = nz + wn + nt * 16 + col;
#pragma unroll
        for (int r = 0; r < 4; ++r)
          Y[(size_t)(mg + r) * CC + ng] = f2bf(acc[mt][nt][r]);
      }
  }
}

// ---------- Flash attention: 128-thr block = 2 indep waves, each 32 q-rows ----------
// qt = 3 - bx/768 (heavy first; 768%8==0 -> uniform qt per XCD, same-bh same-XCD).
__global__ __launch_bounds__(128) void attn(const u16* __restrict__ ws,
                                            float* __restrict__ out) {
  const int bx = blockIdx.x;
  const int qt = 3 - (bx / 768);
  const int bh = bx % 768;
  const int b = bh / HH;
  const int h = bh % HH;

  __shared__ u16 Ps[2][16][72];   // per-wave P^T round-trip: [q][key]

  const int tid = threadIdx.x;
  const int lane = tid & 63;
  const int w = tid >> 6;
  const int quad = lane >> 4;
  const int col = lane & 15;
  const int q0 = qt * 64 + w * 32;   // this wave's 32 q-rows

  const u16* Qg = ws + QOFF;
  const u16* Kg = ws + KOFF;
  const u16* VTg = ws + VOFF;

  // Q B-frags hoisted (pre-scaled by CSC): [n=q=col][k=d]
  s16x8 qf[2][2];
#pragma unroll
  for (int mt = 0; mt < 2; ++mt)
#pragma unroll
    for (int ks = 0; ks < 2; ++ks)
      qf[mt][ks] = *(const s16x8*)(Qg + (size_t)(b * TT + q0 + mt * 16 + col) * CC +
                                   h * DD + ks * 32 + quad * 8);

  f32x4 o[2][4] = {};          // O^T acc: [mt(q16)][dt(d16)]
  float mst[2] = {-1.0e30f, -1.0e30f}, lst[2] = {0.0f, 0.0f};

  for (int kt = 0; kt <= qt; ++kt) {
    // K A-frags: [key = nt*16+col][d]; V^T A-frags: [d = nt*16+col][key]
    s16x8 kf[4][2], vf[4][2];
#pragma unroll
    for (int nt = 0; nt < 4; ++nt)
#pragma unroll
      for (int ks = 0; ks < 2; ++ks) {
        kf[nt][ks] = *(const s16x8*)(Kg + (size_t)(b * TT + kt * 64 + nt * 16 + col) * CC +
                                     h * DD + ks * 32 + quad * 8);
        vf[nt][ks] = *(const s16x8*)(VTg + ((size_t)(bh * DD + nt * 16 + col) * TT +
                                     kt * 64 + ks * 32 + quad * 8));
      }

#pragma unroll
    for (int mt = 0; mt < 2; ++mt) {
      // S^T tiles: row = key = nt*16+quad*4+r, col = q
      f32x4 s[4] = {};
#pragma unroll
      for (int ks = 0; ks < 2; ++ks)
#pragma unroll
        for (int nt = 0; nt < 4; ++nt)
          s[nt] = __builtin_amdgcn_mfma_f32_16x16x32_bf16(kf[nt][ks], qf[mt][ks],
                                                          s[nt], 0, 0, 0);

      // causal mask (diagonal kt only) + per-lane max over this lane's 16 keys
      float rmax = -1.0e30f;
#pragma unroll
      for (int nt = 0; nt < 4; ++nt)
#pragma unroll
        for (int r = 0; r < 4; ++r) {
          float t = s[nt][r];
          if (kt == qt && (nt * 16 + quad * 4 + r) > (w * 32 + mt * 16 + col)) t = -1.0e30f;
          s[nt][r] = t;
          rmax = fmaxf(rmax, t);
        }
      rmax = fmaxf(rmax, __shfl_xor(rmax, 16));
      rmax = fmaxf(rmax, __shfl_xor(rmax, 32));

      float mn = fmaxf(mst[mt], rmax);
      float alpha = exp2f(mst[mt] - mn);
      mst[mt] = mn;

      float lsum = 0.0f;
      unsigned pk[4][2];
#pragma unroll
      for (int nt = 0; nt < 4; ++nt) {
        float p0 = exp2f(s[nt][0] - mn), p1 = exp2f(s[nt][1] - mn);
        float p2 = exp2f(s[nt][2] - mn), p3 = exp2f(s[nt][3] - mn);
        lsum += (p0 + p1) + (p2 + p3);
        pk[nt][0] = (unsigned)f2bf(p0) | ((unsigned)f2bf(p1) << 16);
        pk[nt][1] = (unsigned)f2bf(p2) | ((unsigned)f2bf(p3) << 16);
      }
      lst[mt] = lst[mt] * alpha + lsum;

#pragma unroll
      for (int dt = 0; dt < 4; ++dt)
#pragma unroll
        for (int r = 0; r < 4; ++r) o[mt][dt][r] *= alpha;

      // P^T -> LDS [q][key]: 4 consecutive keys per lane -> b64 writes
      asm volatile("s_waitcnt lgkmcnt(0)" ::: "memory");  // WAR vs prev reads
#pragma unroll
      for (int nt = 0; nt < 4; ++nt)
        *(uint2*)(&Ps[w][col][nt * 16 + quad * 4]) = make_uint2(pk[nt][0], pk[nt][1]);
      asm volatile("s_waitcnt lgkmcnt(0)" ::: "memory");  // own-wave visibility

      s16x8 pf[2];
#pragma unroll
      for (int ks = 0; ks < 2; ++ks)
        pf[ks] = *(const s16x8*)(&Ps[w][col][ks * 32 + quad * 8]);

#pragma unroll
      for (int ks = 0; ks < 2; ++ks)
#pragma unroll
        for (int dt = 0; dt < 4; ++dt)
          o[mt][dt] = __builtin_amdgcn_mfma_f32_16x16x32_bf16(vf[dt][ks], pf[ks],
                                                              o[mt][dt], 0, 0, 0);
    }
  }

  // epilogue: O^T row = d = dt*16+quad*4+r, col = q -> out[b,q,h*64+d]
#pragma unroll
  for (int mt = 0; mt < 2; ++mt) {
    float l = lst[mt];
    l += __shfl_xor(l, 16);
    l += __shfl_xor(l, 32);
    float inv = 1.0f / l;
    int q = q0 + mt * 16 + col;
#pragma unroll
    for (int dt = 0; dt < 4; ++dt) {
      f32x4 res;
#pragma unroll
      for (int r = 0; r < 4; ++r) res[r] = o[mt][dt][r] * inv;
      *(f32x4*)(out + (size_t)(b * TT + q) * CC + h * DD + dt * 16 + quad * 4) = res;
    }
  }
}

extern "C" void kernel_launch(void* const* d_in, const int* in_sizes, int n_in,
                              void* d_out, int out_size, void* d_ws, size_t ws_size,
                              hipStream_t stream) {
  const float* x  = (const float*)d_in[0];
  const float* wq = (const float*)d_in[1];
  const float* wk = (const float*)d_in[2];
  const float* wv = (const float*)d_in[3];
  u16* ws  = (u16*)d_ws;
  float* out = (float*)d_out;

  prep<<<dim3(6144 + 1728), 256, 0, stream>>>(x, wq, wk, wv, ws);
  gemm_qkv<<<dim3(MM / 128, 9), 256, 0, stream>>>(ws);
  attn<<<dim3(BB * HH * 4), 128, 0, stream>>>(ws, out);
}